// Round 2
// baseline (467.124 us; speedup 1.0000x reference)
//
#include <hip/hip_runtime.h>
#include <hip/hip_bf16.h>
#include <math.h>

// Problem constants (match reference)
#define N_GRP 2048
#define LSLOT 64
#define NQ    4096
#define DIM   256
#define NTYPE 64
#define MMEM  131072
#define GSEG  16384
#define BEX   1024

// Workspace float-offsets
#define OFF_SEG   0u            // 16384*256 floats (16 MiB)
#define OFF_QW    4194304u      // 4096*256
#define OFF_MT    5242880u      // 256*256  (MT[j][i] = sum_z Wk[z][i]*Wq[z][j])
#define OFF_VB    5308416u      // 256      (vb[j] = sum_z Wq[z][j]*bk[z])
#define OFF_WB    5308672u      // 256      (wb[i] = sum_z Wk[z][i]*bq[z])
#define OFF_SB    5308928u      // 1  (sb = bq.bk), padded to 8
#define OFF_EM    5308936u      // 1024 ints
#define OFF_CNT   5309960u      // 1 int
#define OFF_NLL   5309964u      // 1 double (float offset 5309964*4 % 8 == 0)
#define OFF_FLAG  5309966u      // 1 int: bool-storage mode (0=int32,1=int8,2=f32)

// Output float-offsets: [0,262144) logit ; then acc ; emr ; nll ; em(1024)
#define OUT_ACC 262144
#define OUT_EMR 262145
#define OUT_NLL 262146
#define OUT_EM  262147

__device__ __forceinline__ bool rd_bool(const void* p, int i, int mode) {
  if (mode == 0) return ((const int*)p)[i] != 0;
  if (mode == 1) return ((const unsigned char*)p)[i] != 0;
  return ((const float*)p)[i] != 0.f;
}

// Precompute MT = Wk^T Wq (layout MT[j][i]), vb, wb, sb; detect bool storage
// mode from typ; init em/cnt/nll. 35 blocks x 256.
__global__ __launch_bounds__(256)
void k_pre(const float* __restrict__ Wq, const float* __restrict__ bq,
           const float* __restrict__ Wk, const float* __restrict__ bk,
           const void* __restrict__ typ, float* __restrict__ ws) {
  int b = blockIdx.x, t = threadIdx.x;
  if (b < 32) {
    int j0 = b * 8;
    float acc[8] = {0.f,0.f,0.f,0.f,0.f,0.f,0.f,0.f};
    for (int z = 0; z < 256; ++z) {
      float wk = Wk[z * 256 + t];                 // coalesced vector load
      const float* wq = Wq + z * 256 + j0;        // uniform -> scalar loads
      #pragma unroll
      for (int u = 0; u < 8; ++u) acc[u] += wq[u] * wk;
    }
    #pragma unroll
    for (int u = 0; u < 8; ++u) ws[OFF_MT + (unsigned)(j0 + u) * 256 + t] = acc[u];
  } else if (b == 32) {
    float a = 0.f;
    for (int z = 0; z < 256; ++z) a += Wq[z * 256 + t] * bk[z];
    ws[OFF_VB + t] = a;
  } else if (b == 33) {
    float a = 0.f;
    for (int z = 0; z < 256; ++z) a += Wk[z * 256 + t] * bq[z];
    ws[OFF_WB + t] = a;
    __shared__ float red[256];
    red[t] = bq[t] * bk[t];
    __syncthreads();
    for (int st = 128; st; st >>= 1) { if (t < st) red[t] += red[t + st]; __syncthreads(); }
    if (t == 0) ws[OFF_SB] = red[0];
  } else {
    // b == 34: bool-mode detection + small-state init
    __shared__ int fl_f, fl_b;
    if (t == 0) { fl_f = 0; fl_b = 0; }
    __syncthreads();
    for (int i = t; i < 4096; i += 256) {
      unsigned wv = ((const unsigned*)typ)[i];
      if (wv == 0x3F800000u) atomicOr(&fl_f, 1);   // float32 1.0 pattern
      else if (wv > 1u)      atomicOr(&fl_b, 1);   // packed-byte pattern
    }
    __syncthreads();
    int* em = (int*)(ws + OFF_EM);
    for (int i = t; i < BEX; i += 256) em[i] = 0x7FFFFFFF;  // segment_min identity
    if (t == 0) {
      *(int*)(ws + OFF_FLAG) = fl_f ? 2 : (fl_b ? 1 : 0);
      *(int*)(ws + OFF_CNT) = 0;
      *(double*)(ws + OFF_NLL) = 0.0;
    }
  }
}

// segment_sum(emb[mem], grp) -> seg[G][256]. grp sorted; one WAVE per segment,
// 4 segments per block, float4 lanes.
__global__ __launch_bounds__(256)
void k_seg(const float* __restrict__ emb, const int* __restrict__ mem,
           const int* __restrict__ grp, float* __restrict__ ws) {
  int t = threadIdx.x;
  int lane = t & 63, w = t >> 6;
  int g = blockIdx.x * 4 + w;
  int lo = 0, hi = MMEM;
  while (lo < hi) { int mid = (lo + hi) >> 1; if (grp[mid] < g) lo = mid + 1; else hi = mid; }
  int lo2 = lo, hi2 = MMEM;
  while (lo2 < hi2) { int mid = (lo2 + hi2) >> 1; if (grp[mid] < g + 1) lo2 = mid + 1; else hi2 = mid; }
  float4 acc = {0.f, 0.f, 0.f, 0.f};
  for (int r = lo; r < lo2; ++r) {
    int tok = mem[r];                              // wave-uniform -> scalar load
    float4 v = *(const float4*)(emb + (size_t)tok * 256 + lane * 4);
    acc.x += v.x; acc.y += v.y; acc.z += v.z; acc.w += v.w;
  }
  *(float4*)(ws + OFF_SEG + (size_t)g * 256 + lane * 4) = acc;
}

// qw[q] = MT^T q + wb  (i.e. Wk^T(Wq q + bq)). 256 blocks x 16 queries.
__global__ __launch_bounds__(256)
void k_qw(const float* __restrict__ q, float* __restrict__ ws) {
  int b = blockIdx.x, t = threadIdx.x;
  int r0 = b * 16;
  const float* MT = ws + OFF_MT;
  float acc[16];
  float wbv = ws[OFF_WB + t];
  #pragma unroll
  for (int r = 0; r < 16; ++r) acc[r] = wbv;
  for (int j = 0; j < 256; j += 4) {
    float m0 = MT[(j + 0) * 256 + t];
    float m1 = MT[(j + 1) * 256 + t];
    float m2 = MT[(j + 2) * 256 + t];
    float m3 = MT[(j + 3) * 256 + t];
    #pragma unroll
    for (int r = 0; r < 16; ++r) {
      float4 q4 = *(const float4*)(q + (size_t)(r0 + r) * 256 + j);  // uniform -> s_load
      acc[r] += q4.x * m0 + q4.y * m1 + q4.z * m2 + q4.w * m3;
    }
  }
  #pragma unroll
  for (int r = 0; r < 16; ++r) ws[OFF_QW + (unsigned)(r0 + r) * 256 + t] = acc[r];
}

// Fused attention + logits + metrics. One block per group (2 queries each).
__global__ __launch_bounds__(256)
void k_attn(const float* __restrict__ q, const float* __restrict__ k,
            const float* __restrict__ Wrel, const float* __restrict__ brel,
            const void* __restrict__ mmask, const int* __restrict__ pos2grp,
            const void* __restrict__ typ, const int* __restrict__ idx,
            float* __restrict__ ws, float* __restrict__ out) {
  int g = blockIdx.x;
  int t = threadIdx.x;
  int lane = t & 63, w = t >> 6;
  __shared__ float qw_l[2][256], qr_l[2][256], att_l[2][256];
  __shared__ float s_l[2][64], p_l[2][64];
  __shared__ float att_p[4][2][64][4];     // per-wave partials for phase D
  __shared__ float cq_l[2];
  __shared__ float nll_l;
  __shared__ int eqcnt_l, all_l[2];
  const int q0 = 2 * g;
  const int mode = *(const int*)(ws + OFF_FLAG);

  // Phase A: stage qw and q rows; compute cq = q.vb + sb per query
  qw_l[0][t] = ws[OFF_QW + (unsigned)q0 * 256 + t];
  qw_l[1][t] = ws[OFF_QW + (unsigned)(q0 + 1) * 256 + t];
  qr_l[0][t] = q[(size_t)q0 * 256 + t];
  qr_l[1][t] = q[(size_t)(q0 + 1) * 256 + t];
  if (t == 0) { eqcnt_l = 0; nll_l = 0.f; all_l[0] = 1; all_l[1] = 1; }
  if (w < 2) {
    const float* qrow = q + (size_t)(q0 + w) * 256;
    float p = 0.f;
    #pragma unroll
    for (int u = 0; u < 4; ++u) p += qrow[lane + 64 * u] * ws[OFF_VB + lane + 64 * u];
    for (int off = 32; off; off >>= 1) p += __shfl_xor(p, off);
    if (lane == 0) cq_l[w] = p + ws[OFF_SB];
  }
  __syncthreads();

  // Phase B: s[q][l] = (qw.k[g,l] + cq)/16, masked -> -inf. Wave w owns 16 l's.
  const float* kg = k + (size_t)g * LSLOT * 256;
  for (int li = 0; li < 16; ++li) {
    int l = w * 16 + li;
    bool valid = rd_bool(mmask, g * LSLOT + l, mode);   // wave-uniform
    if (!valid) {
      if (lane == 0) { s_l[0][l] = -INFINITY; s_l[1][l] = -INFINITY; }
      continue;
    }
    float4 kv = *(const float4*)(kg + l * 256 + lane * 4);
    float4 w0 = *(const float4*)&qw_l[0][lane * 4];
    float4 w1 = *(const float4*)&qw_l[1][lane * 4];
    float s0 = kv.x * w0.x + kv.y * w0.y + kv.z * w0.z + kv.w * w0.w;
    float s1 = kv.x * w1.x + kv.y * w1.y + kv.z * w1.z + kv.w * w1.w;
    for (int off = 32; off; off >>= 1) { s0 += __shfl_xor(s0, off); s1 += __shfl_xor(s1, off); }
    if (lane == 0) {
      s_l[0][l] = (s0 + cq_l[0]) * 0.0625f;
      s_l[1][l] = (s1 + cq_l[1]) * 0.0625f;
    }
  }
  __syncthreads();

  // Phase C: softmax over 64 slots (wave 0 -> q0, wave 1 -> q1)
  if (w < 2) {
    float v = s_l[w][lane];
    float mx = v;
    for (int off = 32; off; off >>= 1) mx = fmaxf(mx, __shfl_xor(mx, off));
    float e = expf(v - mx);                        // -inf -> exactly 0
    float ssum = e;
    for (int off = 32; off; off >>= 1) ssum += __shfl_xor(ssum, off);
    p_l[w][lane] = e / ssum;
  }
  __syncthreads();

  // Phase D: att[q][d] = sum_l p[q][l]*seg[pos2grp[g][l]][d].
  // Wave w handles l = 4*li + w; float4 per lane; cross-wave LDS reduce.
  {
    float4 a0 = {0.f,0.f,0.f,0.f}, a1 = {0.f,0.f,0.f,0.f};
    const float* seg = ws + OFF_SEG;
    const int* pg = pos2grp + g * LSLOT;
    for (int li = 0; li < 16; ++li) {
      int l = li * 4 + w;
      float p0 = p_l[0][l], p1 = p_l[1][l];
      if (p0 == 0.f && p1 == 0.f) continue;        // wave-uniform skip (masked slots)
      int row = pg[l];                             // wave-uniform -> scalar load
      float4 v = *(const float4*)(seg + (size_t)row * 256 + lane * 4);
      a0.x += p0 * v.x; a0.y += p0 * v.y; a0.z += p0 * v.z; a0.w += p0 * v.w;
      a1.x += p1 * v.x; a1.y += p1 * v.y; a1.z += p1 * v.z; a1.w += p1 * v.w;
    }
    *(float4*)&att_p[w][0][lane][0] = a0;
    *(float4*)&att_p[w][1][lane][0] = a1;
  }
  __syncthreads();
  {
    int dl = t >> 2, dc = t & 3;
    #pragma unroll
    for (int qi = 0; qi < 2; ++qi)
      att_l[qi][t] = att_p[0][qi][dl][dc] + att_p[1][qi][dl][dc]
                   + att_p[2][qi][dl][dc] + att_p[3][qi][dl][dc];
  }
  __syncthreads();

  // Phase E: logit[q][tt] = [qrow|att].Wrel[tt] + brel[tt]; stats.
  // Wave w: q = w>>1, tt in [(w&1)*32, +32)
  {
    int cnt = 0, allf = 1;
    float nllp = 0.f;
    int qi = w >> 1;
    int tbase = (w & 1) * 32;
    const float* src = (lane < 32) ? &qr_l[qi][lane * 8] : &att_l[qi][(lane - 32) * 8];
    float4 xa = *(const float4*)src;
    float4 xb = *(const float4*)(src + 4);
    for (int it = 0; it < 32; ++it) {
      int tt = tbase + it;
      const float* wr = Wrel + tt * 512 + lane * 8;
      float4 wa = *(const float4*)wr;
      float4 wb4 = *(const float4*)(wr + 4);
      float d = xa.x * wa.x + xa.y * wa.y + xa.z * wa.z + xa.w * wa.w
              + xb.x * wb4.x + xb.y * wb4.y + xb.z * wb4.z + xb.w * wb4.w;
      for (int off = 32; off; off >>= 1) d += __shfl_xor(d, off);
      if (lane == 0) {
        float lg = d + brel[tt];
        out[(size_t)(q0 + qi) * NTYPE + tt] = lg;
        bool gt = lg > 0.f;
        bool tv = rd_bool(typ, (q0 + qi) * NTYPE + tt, mode);
        bool eqv = (gt == tv);
        cnt += (int)eqv;
        allf &= (int)eqv;
        nllp += fmaxf(lg, 0.f) + log1pf(expf(-fabsf(lg))) - (tv ? lg : 0.f);
      }
    }
    if (lane == 0) {
      atomicAdd(&eqcnt_l, cnt);
      atomicAnd(&all_l[qi], allf);
      atomicAdd(&nll_l, nllp);
    }
  }
  __syncthreads();
  if (t == 0) {
    atomicAdd((int*)(ws + OFF_CNT), eqcnt_l);
    atomicAdd((double*)(ws + OFF_NLL), (double)nll_l);
    int* em = (int*)(ws + OFF_EM);
    atomicMin(&em[idx[q0]], all_l[0]);
    atomicMin(&em[idx[q0 + 1]], all_l[1]);
  }
}

__global__ __launch_bounds__(256)
void k_fin(float* __restrict__ ws, float* __restrict__ out) {
  __shared__ float red[256];
  int t = threadIdx.x;
  const int* em = (const int*)(ws + OFF_EM);
  float s = 0.f;
  for (int i = t; i < BEX; i += 256) {
    float v = (float)em[i];
    out[OUT_EM + i] = v;
    s += v;
  }
  red[t] = s; __syncthreads();
  for (int st = 128; st; st >>= 1) { if (t < st) red[t] += red[t + st]; __syncthreads(); }
  if (t == 0) {
    out[OUT_ACC] = (float)(*(const int*)(ws + OFF_CNT)) / (float)(NQ * NTYPE);
    out[OUT_EMR] = red[0] / (float)BEX;
    out[OUT_NLL] = (float)((*(const double*)(ws + OFF_NLL)) / (double)N_GRP);
  }
}

extern "C" void kernel_launch(void* const* d_in, const int* in_sizes, int n_in,
                              void* d_out, int out_size, void* d_ws, size_t ws_size,
                              hipStream_t stream) {
  const float* q    = (const float*)d_in[0];
  const float* k    = (const float*)d_in[1];
  const float* emb  = (const float*)d_in[2];
  const float* Wq   = (const float*)d_in[3];
  const float* bq   = (const float*)d_in[4];
  const float* Wk   = (const float*)d_in[5];
  const float* bk   = (const float*)d_in[6];
  const float* Wrel = (const float*)d_in[7];
  const float* brel = (const float*)d_in[8];
  const void* mmask   = d_in[9];           // bool m (mode-detected)
  // d_in[10] = qgrp: deterministic repeat_interleave(arange(N_GRP), 2) -> q0 = 2*g, unused
  const int* mem      = (const int*)d_in[11];
  const int* grp      = (const int*)d_in[12];
  const int* pos2grp  = (const int*)d_in[13];
  const void* typ     = d_in[14];          // bool typ (mode-detected)
  const int* idx      = (const int*)d_in[15];
  float* ws  = (float*)d_ws;
  float* out = (float*)d_out;

  k_pre <<<35,     256, 0, stream>>>(Wq, bq, Wk, bk, typ, ws);
  k_seg <<<GSEG/4, 256, 0, stream>>>(emb, mem, grp, ws);
  k_qw  <<<NQ/16,  256, 0, stream>>>(q, ws);
  k_attn<<<N_GRP,  256, 0, stream>>>(q, k, Wrel, brel, mmask, pos2grp, typ, idx, ws, out);
  k_fin <<<1,      256, 0, stream>>>(ws, out);
}

// Round 5
// 386.803 us; speedup vs baseline: 1.2077x; 1.2077x over previous
//
#include <hip/hip_runtime.h>
#include <hip/hip_bf16.h>
#include <math.h>

// Problem constants (match reference)
#define N_GRP 2048
#define LSLOT 64
#define NQ    4096
#define DIM   256
#define NTYPE 64
#define MMEM  131072
#define GSEG  16384
#define BEX   1024

// Workspace float-offsets
#define OFF_SEG   0u            // 16384*256 floats (16 MiB)
#define OFF_QW    4194304u      // 4096*256
#define OFF_MT    5242880u      // 256*256  (MT[j][i] = sum_z Wk[z][i]*Wq[z][j])
#define OFF_VB    5308416u      // 256      (vb[j] = sum_z Wq[z][j]*bk[z])
#define OFF_WB    5308672u      // 256      (wb[i] = sum_z Wk[z][i]*bq[z])
#define OFF_SB    5308928u      // 1  (sb = bq.bk), padded to 8
#define OFF_EM    5308936u      // 1024 ints
#define OFF_CNT   5309960u      // 1 int
#define OFF_NLL   5309964u      // 1 double (float offset 5309964*4 % 8 == 0)
#define OFF_FLAG  5309966u      // 1 int: bool-storage mode (0=int32,1=int8,2=f32)

// Output float-offsets: [0,262144) logit ; then acc ; emr ; nll ; em(1024)
#define OUT_ACC 262144
#define OUT_EMR 262145
#define OUT_NLL 262146
#define OUT_EM  262147

__device__ __forceinline__ bool rd_bool(const void* p, int i, int mode) {
  if (mode == 0) return ((const int*)p)[i] != 0;
  if (mode == 1) return ((const unsigned char*)p)[i] != 0;
  return ((const float*)p)[i] != 0.f;
}

// Precompute MT = Wk^T Wq (layout MT[j][i]), vb, wb, sb; detect bool storage
// mode from typ; init em/cnt/nll. 259 blocks x 256.
__global__ __launch_bounds__(256)
void k_pre(const float* __restrict__ Wq, const float* __restrict__ bq,
           const float* __restrict__ Wk, const float* __restrict__ bk,
           const void* __restrict__ typ, float* __restrict__ ws) {
  int b = blockIdx.x, t = threadIdx.x;
  if (b < 256) {
    int j = b;
    float acc = 0.f;
    #pragma unroll 8
    for (int z = 0; z < 256; ++z)
      acc += Wk[z * 256 + t] * Wq[z * 256 + j];   // coalesced * broadcast
    ws[OFF_MT + (unsigned)j * 256 + t] = acc;
  } else if (b == 256) {
    float a = 0.f;
    #pragma unroll 8
    for (int z = 0; z < 256; ++z) a += Wq[z * 256 + t] * bk[z];
    ws[OFF_VB + t] = a;
  } else if (b == 257) {
    float a = 0.f;
    #pragma unroll 8
    for (int z = 0; z < 256; ++z) a += Wk[z * 256 + t] * bq[z];
    ws[OFF_WB + t] = a;
    __shared__ float red[256];
    red[t] = bq[t] * bk[t];
    __syncthreads();
    for (int st = 128; st; st >>= 1) { if (t < st) red[t] += red[t + st]; __syncthreads(); }
    if (t == 0) ws[OFF_SB] = red[0];
  } else {
    // b == 258: bool-mode detection + small-state init
    __shared__ int fl_f, fl_b;
    if (t == 0) { fl_f = 0; fl_b = 0; }
    __syncthreads();
    for (int i = t; i < 4096; i += 256) {
      unsigned wv = ((const unsigned*)typ)[i];
      if (wv == 0x3F800000u) atomicOr(&fl_f, 1);   // float32 1.0 pattern
      else if (wv > 1u)      atomicOr(&fl_b, 1);   // packed-byte pattern
    }
    __syncthreads();
    int* em = (int*)(ws + OFF_EM);
    for (int i = t; i < BEX; i += 256) em[i] = 0x7FFFFFFF;  // segment_min identity
    if (t == 0) {
      *(int*)(ws + OFF_FLAG) = fl_f ? 2 : (fl_b ? 1 : 0);
      *(int*)(ws + OFF_CNT) = 0;
      *(double*)(ws + OFF_NLL) = 0.0;
    }
  }
}

// Merged: blocks [0,4096) do segment_sum; blocks [4096,4608) do qw GEMV.
// (Independent work; merging removes a launch gap and overlaps seg's HBM
// gather with qw's L2-resident streaming.)
__global__ __launch_bounds__(256)
void k_segqw(const float* __restrict__ emb, const int* __restrict__ mem,
             const int* __restrict__ grp, const float* __restrict__ q,
             float* __restrict__ ws) {
  int t = threadIdx.x;
  if (blockIdx.x < GSEG / 4) {
    // ---- segment_sum(emb[mem], grp) -> seg[G][256]; one WAVE per segment.
    int lane = t & 63, w = t >> 6;
    int g = blockIdx.x * 4 + w;
    int lo = 0, hi = MMEM;
    while (lo < hi) { int mid = (lo + hi) >> 1; if (grp[mid] < g) lo = mid + 1; else hi = mid; }
    int lo2 = lo, hi2 = MMEM;
    while (lo2 < hi2) { int mid = (lo2 + hi2) >> 1; if (grp[mid] < g + 1) lo2 = mid + 1; else hi2 = mid; }
    int n = lo2 - lo;
    int nv = n < 64 ? n : 64;
    int tok = (lane < nv) ? mem[lo + lane] : 0;    // one coalesced batch load
    float4 acc = {0.f, 0.f, 0.f, 0.f};
    int r = 0;
    for (; r + 4 <= nv; r += 4) {
      int t0 = __shfl(tok, r + 0), t1 = __shfl(tok, r + 1);
      int t2 = __shfl(tok, r + 2), t3 = __shfl(tok, r + 3);
      float4 v0 = *(const float4*)(emb + (size_t)t0 * 256 + lane * 4);
      float4 v1 = *(const float4*)(emb + (size_t)t1 * 256 + lane * 4);
      float4 v2 = *(const float4*)(emb + (size_t)t2 * 256 + lane * 4);
      float4 v3 = *(const float4*)(emb + (size_t)t3 * 256 + lane * 4);
      acc.x += (v0.x + v1.x) + (v2.x + v3.x);
      acc.y += (v0.y + v1.y) + (v2.y + v3.y);
      acc.z += (v0.z + v1.z) + (v2.z + v3.z);
      acc.w += (v0.w + v1.w) + (v2.w + v3.w);
    }
    for (; r < nv; ++r) {
      int tr = __shfl(tok, r);
      float4 v = *(const float4*)(emb + (size_t)tr * 256 + lane * 4);
      acc.x += v.x; acc.y += v.y; acc.z += v.z; acc.w += v.w;
    }
    for (int rr = lo + 64; rr < lo2; ++rr) {       // overflow fallback (P ~ 0)
      int tr = mem[rr];
      float4 v = *(const float4*)(emb + (size_t)tr * 256 + lane * 4);
      acc.x += v.x; acc.y += v.y; acc.z += v.z; acc.w += v.w;
    }
    *(float4*)(ws + OFF_SEG + (size_t)g * 256 + lane * 4) = acc;
  } else {
    // ---- qw[r] = MT^T q[r] + wb  (i.e. Wk^T(Wq q + bq)); 8 queries/block.
    int b = blockIdx.x - GSEG / 4;
    int r0 = b * 8;
    const float* MT = ws + OFF_MT;
    float acc[8];
    float wbv = ws[OFF_WB + t];
    #pragma unroll
    for (int r = 0; r < 8; ++r) acc[r] = wbv;
    for (int j = 0; j < 256; j += 4) {
      float m0 = MT[(j + 0) * 256 + t];
      float m1 = MT[(j + 1) * 256 + t];
      float m2 = MT[(j + 2) * 256 + t];
      float m3 = MT[(j + 3) * 256 + t];
      #pragma unroll
      for (int r = 0; r < 8; ++r) {
        float4 q4 = *(const float4*)(q + (size_t)(r0 + r) * 256 + j);  // broadcast
        acc[r] += q4.x * m0 + q4.y * m1 + q4.z * m2 + q4.w * m3;
      }
    }
    #pragma unroll
    for (int r = 0; r < 8; ++r) ws[OFF_QW + (unsigned)(r0 + r) * 256 + t] = acc[r];
  }
}

// Fused attention + logits + metrics. One block per group (2 queries each).
__global__ __launch_bounds__(256)
void k_attn(const float* __restrict__ q, const float* __restrict__ k,
            const float* __restrict__ Wrel, const float* __restrict__ brel,
            const void* __restrict__ mmask, const int* __restrict__ pos2grp,
            const void* __restrict__ typ, const int* __restrict__ idx,
            float* __restrict__ ws, float* __restrict__ out) {
  int g = blockIdx.x;
  int t = threadIdx.x;
  int lane = t & 63, w = t >> 6;
  __shared__ float qw_l[2][256], qr_l[2][256], att_l[2][256];
  __shared__ float s_raw[2][64], p_l[2][64];   // s_raw reused for logits in E
  __shared__ float att_p[4][2][64][4];         // per-wave partials for phase D
  __shared__ float cq_l[2];
  __shared__ float nll_l;
  __shared__ int eqcnt_l, all_l[2];
  const int q0 = 2 * g;
  const int mode = *(const int*)(ws + OFF_FLAG);

  // Phase A: stage qw and q rows; compute cq = q.vb + sb per query
  qw_l[0][t] = ws[OFF_QW + (unsigned)q0 * 256 + t];
  qw_l[1][t] = ws[OFF_QW + (unsigned)(q0 + 1) * 256 + t];
  qr_l[0][t] = q[(size_t)q0 * 256 + t];
  qr_l[1][t] = q[(size_t)(q0 + 1) * 256 + t];
  if (t == 0) { eqcnt_l = 0; nll_l = 0.f; }
  if (w < 2) {
    const float* qrow = q + (size_t)(q0 + w) * 256;
    float p = 0.f;
    #pragma unroll
    for (int u = 0; u < 4; ++u) p += qrow[lane + 64 * u] * ws[OFF_VB + lane + 64 * u];
    for (int off = 32; off; off >>= 1) p += __shfl_xor(p, off);
    if (lane == 0) cq_l[w] = p + ws[OFF_SB];
  }
  __syncthreads();

  // Phase B: raw scores for ALL 64 slots, branchless + shuffle-light.
  // Quad (lane>>2)=local slot, (lane&3)=dim quad; each thread: 64 dims.
  {
    int sl = w * 16 + (lane >> 2);                 // slot 0..63
    int c4 = lane & 3;
    const float* kr = k + (size_t)g * LSLOT * 256 + (size_t)sl * 256 + c4 * 4;
    float s0 = 0.f, s1 = 0.f;
    #pragma unroll
    for (int j = 0; j < 16; ++j) {
      float4 kv = *(const float4*)(kr + j * 16);
      float4 w0 = *(const float4*)&qw_l[0][j * 16 + c4 * 4];
      float4 w1 = *(const float4*)&qw_l[1][j * 16 + c4 * 4];
      s0 += kv.x * w0.x + kv.y * w0.y + kv.z * w0.z + kv.w * w0.w;
      s1 += kv.x * w1.x + kv.y * w1.y + kv.z * w1.z + kv.w * w1.w;
    }
    s0 += __shfl_xor(s0, 1); s0 += __shfl_xor(s0, 2);
    s1 += __shfl_xor(s1, 1); s1 += __shfl_xor(s1, 2);
    if (c4 == 0) { s_raw[0][sl] = s0; s_raw[1][sl] = s1; }
  }
  __syncthreads();

  // Phase C: mask + scale + softmax over 64 slots (wave 0 -> q0, wave 1 -> q1)
  if (w < 2) {
    bool valid = rd_bool(mmask, g * LSLOT + lane, mode);  // per-lane coalesced
    float v = valid ? (s_raw[w][lane] + cq_l[w]) * 0.0625f : -INFINITY;
    float mx = v;
    for (int off = 32; off; off >>= 1) mx = fmaxf(mx, __shfl_xor(mx, off));
    float e = expf(v - mx);                        // -inf -> exactly 0
    float ssum = e;
    for (int off = 32; off; off >>= 1) ssum += __shfl_xor(ssum, off);
    p_l[w][lane] = e / ssum;
  }
  __syncthreads();

  // Phase D: att[q][d] = sum_l p[q][l]*seg[pos2grp[g][l]][d].
  // Wave w handles l = 4*li + w; float4 per lane; cross-wave LDS reduce.
  {
    float4 a0 = {0.f,0.f,0.f,0.f}, a1 = {0.f,0.f,0.f,0.f};
    const float* seg = ws + OFF_SEG;
    const int* pg = pos2grp + g * LSLOT;
    #pragma unroll 4
    for (int li = 0; li < 16; ++li) {
      int l = li * 4 + w;
      float p0 = p_l[0][l], p1 = p_l[1][l];
      if (p0 == 0.f && p1 == 0.f) continue;        // wave-uniform skip (masked slots)
      int row = pg[l];                             // wave-uniform -> scalar load
      float4 v = *(const float4*)(seg + (size_t)row * 256 + lane * 4);
      a0.x += p0 * v.x; a0.y += p0 * v.y; a0.z += p0 * v.z; a0.w += p0 * v.w;
      a1.x += p1 * v.x; a1.y += p1 * v.y; a1.z += p1 * v.z; a1.w += p1 * v.w;
    }
    *(float4*)&att_p[w][0][lane][0] = a0;
    *(float4*)&att_p[w][1][lane][0] = a1;
  }
  __syncthreads();
  {
    int dl = t >> 2, dc = t & 3;
    #pragma unroll
    for (int qi = 0; qi < 2; ++qi)
      att_l[qi][t] = att_p[0][qi][dl][dc] + att_p[1][qi][dl][dc]
                   + att_p[2][qi][dl][dc] + att_p[3][qi][dl][dc];
  }
  __syncthreads();

  // Phase E: logit[q][tt] = [qrow|att].Wrel[tt] + brel[tt].
  // Quad-mapped like phase B: wave w -> qi=w>>1, tthalf=w&1; per outer h,
  // quad (lane>>2) owns one tt, covers 512 dims as float4 strided by 16.
  // 4 shuffles/wave total (vs 192 in the serial version).
  {
    int qi = w >> 1;
    int c4 = lane & 3;
    #pragma unroll
    for (int h = 0; h < 2; ++h) {
      int tt = (w & 1) * 32 + h * 16 + (lane >> 2);
      const float* wr = Wrel + (size_t)tt * 512 + c4 * 4;
      float s = 0.f;
      #pragma unroll
      for (int j = 0; j < 16; ++j) {
        float4 wv = *(const float4*)(wr + j * 16);
        float4 xv = *(const float4*)&qr_l[qi][j * 16 + c4 * 4];
        s += wv.x * xv.x + wv.y * xv.y + wv.z * xv.z + wv.w * xv.w;
      }
      #pragma unroll
      for (int j = 0; j < 16; ++j) {
        float4 wv = *(const float4*)(wr + 1024 + j * 16);
        float4 xv = *(const float4*)&att_l[qi][j * 16 + c4 * 4];
        s += wv.x * xv.x + wv.y * xv.y + wv.z * xv.z + wv.w * xv.w;
      }
      s += __shfl_xor(s, 1); s += __shfl_xor(s, 2);
      if (c4 == 0) s_raw[qi][tt] = s;              // s_raw reused as logit buf
    }
  }
  __syncthreads();

  // Stats: waves 0,1 (qi=w), lane=tt. Coalesced logit store + ballot stats.
  if (w < 2) {
    int qi = w;
    float lg = s_raw[qi][lane] + brel[lane];
    out[(size_t)(q0 + qi) * NTYPE + lane] = lg;    // one coalesced 64-lane store
    bool gt = lg > 0.f;
    bool tv = rd_bool(typ, (q0 + qi) * NTYPE + lane, mode);
    bool eqv = (gt == tv);
    unsigned long long mask = __ballot(eqv);
    float nllp = fmaxf(lg, 0.f) + log1pf(expf(-fabsf(lg))) - (tv ? lg : 0.f);
    for (int off = 32; off; off >>= 1) nllp += __shfl_xor(nllp, off);
    if (lane == 0) {
      all_l[qi] = (mask == 0xFFFFFFFFFFFFFFFFull) ? 1 : 0;
      atomicAdd(&eqcnt_l, (int)__popcll(mask));
      atomicAdd(&nll_l, nllp);
    }
  }
  __syncthreads();
  if (t == 0) {
    atomicAdd((int*)(ws + OFF_CNT), eqcnt_l);
    atomicAdd((double*)(ws + OFF_NLL), (double)nll_l);
    int* em = (int*)(ws + OFF_EM);
    atomicMin(&em[idx[q0]], all_l[0]);
    atomicMin(&em[idx[q0 + 1]], all_l[1]);
  }
}

__global__ __launch_bounds__(256)
void k_fin(float* __restrict__ ws, float* __restrict__ out) {
  __shared__ float red[256];
  int t = threadIdx.x;
  const int* em = (const int*)(ws + OFF_EM);
  float s = 0.f;
  for (int i = t; i < BEX; i += 256) {
    float v = (float)em[i];
    out[OUT_EM + i] = v;
    s += v;
  }
  red[t] = s; __syncthreads();
  for (int st = 128; st; st >>= 1) { if (t < st) red[t] += red[t + st]; __syncthreads(); }
  if (t == 0) {
    out[OUT_ACC] = (float)(*(const int*)(ws + OFF_CNT)) / (float)(NQ * NTYPE);
    out[OUT_EMR] = red[0] / (float)BEX;
    out[OUT_NLL] = (float)((*(const double*)(ws + OFF_NLL)) / (double)N_GRP);
  }
}

extern "C" void kernel_launch(void* const* d_in, const int* in_sizes, int n_in,
                              void* d_out, int out_size, void* d_ws, size_t ws_size,
                              hipStream_t stream) {
  const float* q    = (const float*)d_in[0];
  const float* k    = (const float*)d_in[1];
  const float* emb  = (const float*)d_in[2];
  const float* Wq   = (const float*)d_in[3];
  const float* bq   = (const float*)d_in[4];
  const float* Wk   = (const float*)d_in[5];
  const float* bk   = (const float*)d_in[6];
  const float* Wrel = (const float*)d_in[7];
  const float* brel = (const float*)d_in[8];
  const void* mmask   = d_in[9];           // bool m (mode-detected)
  // d_in[10] = qgrp: deterministic repeat_interleave(arange(N_GRP), 2) -> q0 = 2*g, unused
  const int* mem      = (const int*)d_in[11];
  const int* grp      = (const int*)d_in[12];
  const int* pos2grp  = (const int*)d_in[13];
  const void* typ     = d_in[14];          // bool typ (mode-detected)
  const int* idx      = (const int*)d_in[15];
  float* ws  = (float*)d_ws;
  float* out = (float*)d_out;

  k_pre  <<<259,            256, 0, stream>>>(Wq, bq, Wk, bk, typ, ws);
  k_segqw<<<GSEG/4 + NQ/8,  256, 0, stream>>>(emb, mem, grp, q, ws);
  k_attn <<<N_GRP,          256, 0, stream>>>(q, k, Wrel, brel, mmask, pos2grp, typ, idx, ws, out);
  k_fin  <<<1,              256, 0, stream>>>(ws, out);
}